// Round 18
// baseline (371.424 us; speedup 1.0000x reference)
//
#include <hip/hip_runtime.h>
#include <hip/hip_bf16.h>

#define C_NUM 100000
#define D_EMB 512
#define N_BATCH 512
#define SCALE_F 30.0f
#define MARGIN_F 0.4f
#define H_F 0.333f
#define NTC 196              // ceil(100000/512) class tiles (512-wide)
#define PST 200              // padded partial stride (per row)

typedef __attribute__((ext_vector_type(8))) short bf16x8;
typedef __attribute__((ext_vector_type(4))) short bf16x4;
typedef __attribute__((ext_vector_type(4))) float f32x4;
typedef __attribute__((ext_vector_type(16))) float f32x16;

static __device__ __forceinline__ short f2bf(float f) {
  __hip_bfloat16 h = __float2bfloat16(f);
  union { __hip_bfloat16 b; short s; } u;
  u.b = h;
  return u.s;
}

static __device__ __forceinline__ float sq4(f32x4 v) {
  return v[0]*v[0] + v[1]*v[1] + v[2]*v[2] + v[3]*v[3];
}

// async global -> LDS: 16 B/lane; dest = wave-uniform base + lane*16
static __device__ __forceinline__ void gload16(const void* g, void* l) {
  __builtin_amdgcn_global_load_lds(
      (const __attribute__((address_space(1))) void*)g,
      (__attribute__((address_space(3))) void*)l, 16, 0, 0);
}

// ---------------------------------------------------------------------------
// Kernel 1: per-row L2 norm of embeddings; unit-normalized rows as bf16.
// ---------------------------------------------------------------------------
__global__ __launch_bounds__(64) void k_rownorm(const float* __restrict__ emb,
                                                short* __restrict__ Aunit,
                                                float* __restrict__ norms) {
  const int i = blockIdx.x;
  const int l = threadIdx.x;
  const f32x4* row = reinterpret_cast<const f32x4*>(emb + (size_t)i * D_EMB);
  f32x4 v0 = row[l];
  f32x4 v1 = row[l + 64];
  float ss = sq4(v0) + sq4(v1);
#pragma unroll
  for (int m = 1; m < 64; m <<= 1) ss += __shfl_xor(ss, m);
  float nrm = sqrtf(ss);
  float inv = 1.0f / nrm;
  bf16x4 o0, o1;
#pragma unroll
  for (int q = 0; q < 4; ++q) { o0[q] = f2bf(v0[q] * inv); o1[q] = f2bf(v1[q] * inv); }
  bf16x4* dst = reinterpret_cast<bf16x4*>(Aunit + (size_t)i * D_EMB);
  dst[l] = o0;
  dst[l + 64] = o1;
  if (l == 0) norms[i] = nrm;
}

// ---------------------------------------------------------------------------
// Kernel 2: batch mean / unbiased std -> adaptive margin per row.
// ---------------------------------------------------------------------------
__global__ __launch_bounds__(512) void k_stats(const float* __restrict__ norms,
                                               float* __restrict__ marg) {
  __shared__ float red[8];
  const int t = threadIdx.x;
  const int lane = t & 63, wid = t >> 6;
  float x = norms[t];
  float s = x;
#pragma unroll
  for (int m = 1; m < 64; m <<= 1) s += __shfl_xor(s, m);
  if (lane == 0) red[wid] = s;
  __syncthreads();
  float tot = 0.f;
#pragma unroll
  for (int q = 0; q < 8; ++q) tot += red[q];
  const float mean = tot / 512.f;
  __syncthreads();
  float d = x - mean;
  float s2 = d * d;
#pragma unroll
  for (int m = 1; m < 64; m <<= 1) s2 += __shfl_xor(s2, m);
  if (lane == 0) red[wid] = s2;
  __syncthreads();
  float tot2 = 0.f;
#pragma unroll
  for (int q = 0; q < 8; ++q) tot2 += red[q];
  const float stdv = sqrtf(tot2 / 511.f);   // ddof=1
  float msc = (x - mean) / (stdv + H_F);
  msc = fminf(1.f, fmaxf(-1.f, msc));
  marg[t] = MARGIN_F * (1.f + msc);
}

// ---------------------------------------------------------------------------
// Kernel 3: barrier-free K-loop at 2 waves/SIMD (fixes R16's 1-wave latency
// exposure). 512 thr = 8 waves; block = 128 rows x 512 cls.
// - A (128x512 bf16 = 128 KB) staged ONCE (pre-swizzled (row&15)<<4); the
//   vmcnt(12)+barrier after it is the only block barrier before the epilogue.
// - Wave w privately owns cls [w*64, w*64+64): 3-deep reg pipeline streams W
//   in 16-k chunks -> cvt -> ds_write into private [64][48B] buffer (single-
//   buffered: per-wave DS ops are in-order) -> ds_read b-frags -> MFMA.
// - Per wave 128 rows x 64 cls = 8 named f32x16 accs (128 regs); budget is
//   256/wave at 1 block/CU -> no spill pressure.
// ---------------------------------------------------------------------------
__global__ __launch_bounds__(512, 2) void k_main(const short* __restrict__ Aunit,
                                                 const float* __restrict__ weight,
                                                 const int* __restrict__ labels,
                                                 const float* __restrict__ marg,
                                                 float* __restrict__ partial,
                                                 float* __restrict__ tlogit) {
  __shared__ alignas(16) char Astat[131072];   // [128 rows][1024 B] bf16, swizzled
  __shared__ alignas(16) char Wsl[8][3072];    // per-wave [64 cls][48 B] chunk buf
  __shared__ float winv[8][64];
  __shared__ float rowsumF[128];

  const int bid = blockIdx.x;
  const int grp = bid >> 5, within = bid & 31;
  const int rt = within >> 3;                  // 0..3
  const int ct = grp * 8 + (within & 7);       // 0..199
  if (ct >= NTC) return;

  const int tid = threadIdx.x;                 // 0..511
  const int w = tid >> 6, lane = tid & 63;
  const int l31 = lane & 31, lhi = lane >> 5;

  if (tid < 128) rowsumF[tid] = 0.f;

  // ---- A stage: 16 rounds; wave w stages row (round*8 + w) each round ----
  {
    const char* Abase = (const char*)Aunit + (size_t)(rt * 128) * 1024;
#pragma unroll
    for (int round = 0; round < 16; ++round) {
      const int row = round * 8 + w;
      const int kb = (lane * 16) ^ ((row & 15) << 4);   // pre-swizzled source
      gload16(Abase + (size_t)row * 1024 + kb, &Astat[row * 1024]);
    }
  }

  // ---- W roles: lane covers (cls = r*16 + (lane>>2), su = lane&3) ----
  const int su = lane & 3;
  const int cq = lane >> 2;      // 0..15
  const float* wsrc0; const float* wsrc1; const float* wsrc2; const float* wsrc3;
  int wd0, wd1, wd2, wd3;
  {
    int c0 = 0 * 16 + cq, c1 = 1 * 16 + cq, c2 = 2 * 16 + cq, c3 = 3 * 16 + cq;
    int g0 = ct * 512 + w * 64 + c0; if (g0 > C_NUM - 1) g0 = C_NUM - 1;
    int g1 = ct * 512 + w * 64 + c1; if (g1 > C_NUM - 1) g1 = C_NUM - 1;
    int g2 = ct * 512 + w * 64 + c2; if (g2 > C_NUM - 1) g2 = C_NUM - 1;
    int g3 = ct * 512 + w * 64 + c3; if (g3 > C_NUM - 1) g3 = C_NUM - 1;
    wsrc0 = weight + (size_t)g0 * D_EMB + su * 4;
    wsrc1 = weight + (size_t)g1 * D_EMB + su * 4;
    wsrc2 = weight + (size_t)g2 * D_EMB + su * 4;
    wsrc3 = weight + (size_t)g3 * D_EMB + su * 4;
    wd0 = c0 * 48 + su * 8; wd1 = c1 * 48 + su * 8;
    wd2 = c2 * 48 + su * 8; wd3 = c3 * 48 + su * 8;
  }
  char* Wme = &Wsl[w][0];

  // compute-side offsets
  const int xa = (l31 & 15) << 4;              // A read swizzle
  const int bb0 = (l31) * 48 + lhi * 16;       // b-frag cls l31
  const int bb1 = (32 + l31) * 48 + lhi * 16;  // b-frag cls 32+l31

  f32x16 a00, a01, a10, a11, a20, a21, a30, a31;
#pragma unroll
  for (int q = 0; q < 16; ++q) {
    a00[q] = 0.f; a01[q] = 0.f; a10[q] = 0.f; a11[q] = 0.f;
    a20[q] = 0.f; a21[q] = 0.f; a30[q] = 0.f; a31[q] = 0.f;
  }
  float ssq0 = 0.f, ssq1 = 0.f, ssq2 = 0.f, ssq3 = 0.f;

  f32x4 S00, S01, S02, S03;    // W set for chunk c
  f32x4 S10, S11, S12, S13;    // chunk c+1
  f32x4 S20, S21, S22, S23;    // chunk c+2

#define WLOADSET(R0,R1,R2,R3,C) { \
    const int fo = (C) * 16; \
    R0 = *(const f32x4*)(wsrc0 + fo); R1 = *(const f32x4*)(wsrc1 + fo); \
    R2 = *(const f32x4*)(wsrc2 + fo); R3 = *(const f32x4*)(wsrc3 + fo); }

#define PHASE(R0,R1,R2,R3,C) { \
    ssq0 += sq4(R0); ssq1 += sq4(R1); ssq2 += sq4(R2); ssq3 += sq4(R3); \
    { bf16x4 t0, t1, t2, t3; \
      _Pragma("unroll") \
      for (int e = 0; e < 4; ++e) { t0[e] = f2bf(R0[e]); t1[e] = f2bf(R1[e]); \
                                    t2[e] = f2bf(R2[e]); t3[e] = f2bf(R3[e]); } \
      *(bf16x4*)(Wme + wd0) = t0; *(bf16x4*)(Wme + wd1) = t1; \
      *(bf16x4*)(Wme + wd2) = t2; *(bf16x4*)(Wme + wd3) = t3; } \
    asm volatile("s_waitcnt lgkmcnt(0)" ::: "memory"); \
    __builtin_amdgcn_sched_barrier(0); \
    { int nc = (C) + 3; if (nc > 31) nc = 31; \
      WLOADSET(R0, R1, R2, R3, nc); } \
    { const int kb = (C) * 32 + lhi * 16; \
      bf16x8 af0 = *(const bf16x8*)(Astat + (0 * 32 + l31) * 1024 + (kb ^ xa)); \
      bf16x8 af1 = *(const bf16x8*)(Astat + (1 * 32 + l31) * 1024 + (kb ^ xa)); \
      bf16x8 af2 = *(const bf16x8*)(Astat + (2 * 32 + l31) * 1024 + (kb ^ xa)); \
      bf16x8 af3 = *(const bf16x8*)(Astat + (3 * 32 + l31) * 1024 + (kb ^ xa)); \
      bf16x8 bf0 = *(const bf16x8*)(Wme + bb0); \
      bf16x8 bf1 = *(const bf16x8*)(Wme + bb1); \
      __builtin_amdgcn_s_setprio(1); \
      a00 = __builtin_amdgcn_mfma_f32_32x32x16_bf16(af0, bf0, a00, 0, 0, 0); \
      a01 = __builtin_amdgcn_mfma_f32_32x32x16_bf16(af0, bf1, a01, 0, 0, 0); \
      a10 = __builtin_amdgcn_mfma_f32_32x32x16_bf16(af1, bf0, a10, 0, 0, 0); \
      a11 = __builtin_amdgcn_mfma_f32_32x32x16_bf16(af1, bf1, a11, 0, 0, 0); \
      a20 = __builtin_amdgcn_mfma_f32_32x32x16_bf16(af2, bf0, a20, 0, 0, 0); \
      a21 = __builtin_amdgcn_mfma_f32_32x32x16_bf16(af2, bf1, a21, 0, 0, 0); \
      a30 = __builtin_amdgcn_mfma_f32_32x32x16_bf16(af3, bf0, a30, 0, 0, 0); \
      a31 = __builtin_amdgcn_mfma_f32_32x32x16_bf16(af3, bf1, a31, 0, 0, 0); \
      __builtin_amdgcn_s_setprio(0); } }

  // ---- prologue: W pipeline 3-deep; drain A; single barrier ----
  WLOADSET(S00, S01, S02, S03, 0);
  WLOADSET(S10, S11, S12, S13, 1);
  WLOADSET(S20, S21, S22, S23, 2);
  __builtin_amdgcn_sched_barrier(0);
  asm volatile("s_waitcnt vmcnt(12)" ::: "memory");   // 16 A gloads drained; W flying
  __builtin_amdgcn_s_barrier();                        // A visible to all waves
  __builtin_amdgcn_sched_barrier(0);

  // ---- 32 chunks of 16 k, no barriers ----
  for (int i = 0; i < 10; ++i) {
    PHASE(S00, S01, S02, S03, 3 * i + 0);
    PHASE(S10, S11, S12, S13, 3 * i + 1);
    PHASE(S20, S21, S22, S23, 3 * i + 2);
  }
  PHASE(S00, S01, S02, S03, 30);
  PHASE(S10, S11, S12, S13, 31);

  // ---- per-class 1/||w|| (wave-local) ----
  {
    float s0 = ssq0, s1 = ssq1, s2 = ssq2, s3 = ssq3;
    s0 += __shfl_xor(s0, 1); s0 += __shfl_xor(s0, 2);
    s1 += __shfl_xor(s1, 1); s1 += __shfl_xor(s1, 2);
    s2 += __shfl_xor(s2, 1); s2 += __shfl_xor(s2, 2);
    s3 += __shfl_xor(s3, 1); s3 += __shfl_xor(s3, 2);
    if (su == 0) {
      winv[w][0 * 16 + cq] = (s0 > 0.f) ? rsqrtf(s0) : 0.f;
      winv[w][1 * 16 + cq] = (s1 > 0.f) ? rsqrtf(s1) : 0.f;
      winv[w][2 * 16 + cq] = (s2 > 0.f) ? rsqrtf(s2) : 0.f;
      winv[w][3 * 16 + cq] = (s3 > 0.f) ? rsqrtf(s3) : 0.f;
    }
  }
  asm volatile("s_waitcnt lgkmcnt(0)" ::: "memory");
  const float wv0 = winv[w][l31];
  const float wv1 = winv[w][32 + l31];

  // ---- epilogue: margin at label, per-row exp sums over this wave's 64 cls ----
  // C/D layout: col = lane&31, row = (reg&3) + 8*(reg>>2) + 4*(lane>>5)
  const int gc0 = ct * 512 + w * 64 + l31;
  const int gc1 = gc0 + 32;
  const bool ok0 = gc0 < C_NUM;
  const bool ok1 = gc1 < C_NUM;
#pragma unroll
  for (int mi = 0; mi < 4; ++mi) {
#pragma unroll
    for (int r = 0; r < 16; ++r) {
      const int rowf = (r & 3) + 8 * (r >> 2) + 4 * lhi;
      const int rloc = mi * 32 + rowf;
      const int R = rt * 128 + rloc;
      const int lab = labels[R];
      const float av0 = (mi == 0) ? a00[r] : (mi == 1) ? a10[r] : (mi == 2) ? a20[r] : a30[r];
      const float av1 = (mi == 0) ? a01[r] : (mi == 1) ? a11[r] : (mi == 2) ? a21[r] : a31[r];
      const float c0v = av0 * wv0;
      const float c1v = av1 * wv1;
      float lg0 = SCALE_F * c0v;
      float lg1 = SCALE_F * c1v;
      if (lab == gc0) {
        float ctv = fminf(1.f, fmaxf(-1.f, c0v));
        float lt = SCALE_F * cosf(acosf(ctv) + marg[R]);
        lg0 = lt; tlogit[R] = lt;
      }
      if (lab == gc1) {
        float ctv = fminf(1.f, fmaxf(-1.f, c1v));
        float lt = SCALE_F * cosf(acosf(ctv) + marg[R]);
        lg1 = lt; tlogit[R] = lt;
      }
      float v = (ok0 ? __expf(lg0) : 0.f) + (ok1 ? __expf(lg1) : 0.f);
      v += __shfl_xor(v, 1);
      v += __shfl_xor(v, 2);
      v += __shfl_xor(v, 4);
      v += __shfl_xor(v, 8);
      v += __shfl_xor(v, 16);
      if (l31 == 0) atomicAdd(&rowsumF[rloc], v);
    }
  }
  __syncthreads();
  if (tid < 128)
    partial[(size_t)(rt * 128 + tid) * PST + ct] = rowsumF[tid];
#undef WLOADSET
#undef PHASE
}

// ---------------------------------------------------------------------------
// Kernel 4: per-row reduce (coalesced): term[r] = log(sum_ct partial[r][ct]) - tlogit[r]
// ---------------------------------------------------------------------------
__global__ __launch_bounds__(64) void k_reduce(const float* __restrict__ partial,
                                               const float* __restrict__ tlogit,
                                               float* __restrict__ term) {
  const int r = blockIdx.x;
  const int l = threadIdx.x;
  const float* row = partial + (size_t)r * PST;
  float s = 0.f;
  for (int b = l; b < NTC; b += 64)
    s += row[b];
#pragma unroll
  for (int m = 1; m < 64; m <<= 1) s += __shfl_xor(s, m);
  if (l == 0) term[r] = logf(s) - tlogit[r];
}

// ---------------------------------------------------------------------------
// Kernel 5: loss = mean(term)
// ---------------------------------------------------------------------------
__global__ __launch_bounds__(512) void k_final(const float* __restrict__ term,
                                               float* __restrict__ out) {
  __shared__ float red[8];
  const int t = threadIdx.x;
  const int lane = t & 63, wid = t >> 6;
  float v = term[t];
#pragma unroll
  for (int m = 1; m < 64; m <<= 1) v += __shfl_xor(v, m);
  if (lane == 0) red[wid] = v;
  __syncthreads();
  if (t == 0) {
    float tot = 0.f;
#pragma unroll
    for (int q = 0; q < 8; ++q) tot += red[q];
    out[0] = tot / 512.f;
  }
}

extern "C" void kernel_launch(void* const* d_in, const int* in_sizes, int n_in,
                              void* d_out, int out_size, void* d_ws, size_t ws_size,
                              hipStream_t stream) {
  const float* emb    = (const float*)d_in[0];
  const int*   labels = (const int*)d_in[1];
  const float* weight = (const float*)d_in[2];
  float* out = (float*)d_out;

  char* ws = (char*)d_ws;
  short* Aunit   = (short*)ws;                        // 512*512*2 = 524288 B
  float* norms   = (float*)(ws + 524288);             // 2 KiB
  float* marg    = (float*)(ws + 524288 + 2048);      // 2 KiB
  float* tlog    = (float*)(ws + 524288 + 4096);      // 2 KiB
  float* term    = (float*)(ws + 524288 + 6144);      // 2 KiB
  float* partial = (float*)(ws + 524288 + 8192);      // 512*200*4 = 409600 B

  k_rownorm<<<N_BATCH, 64, 0, stream>>>(emb, Aunit, norms);
  k_stats<<<1, 512, 0, stream>>>(norms, marg);
  k_main<<<25 * 32, 512, 0, stream>>>(Aunit, weight, labels, marg, partial, tlog);
  k_reduce<<<N_BATCH, 64, 0, stream>>>(partial, tlog, term);
  k_final<<<1, 512, 0, stream>>>(term, out);
}

// Round 19
// 134.411 us; speedup vs baseline: 2.7633x; 2.7633x over previous
//
#include <hip/hip_runtime.h>
#include <hip/hip_bf16.h>

#define C_NUM 100000
#define D_EMB 512
#define N_BATCH 512
#define SCALE_F 30.0f
#define MARGIN_F 0.4f
#define H_F 0.333f
#define NT2 782              // ceil(100000/128) class tiles
#define PST 784              // padded partial stride (per row)

typedef __attribute__((ext_vector_type(8))) short bf16x8;
typedef __attribute__((ext_vector_type(4))) short bf16x4;
typedef __attribute__((ext_vector_type(4))) float f32x4;
typedef __attribute__((ext_vector_type(16))) float f32x16;

static __device__ __forceinline__ short f2bf(float f) {
  __hip_bfloat16 h = __float2bfloat16(f);
  union { __hip_bfloat16 b; short s; } u;
  u.b = h;
  return u.s;
}

static __device__ __forceinline__ float sq4(f32x4 v) {
  return v[0]*v[0] + v[1]*v[1] + v[2]*v[2] + v[3]*v[3];
}

// async global -> LDS: 16 B/lane; dest = wave-uniform base + lane*16
static __device__ __forceinline__ void gload16(const void* g, void* l) {
  __builtin_amdgcn_global_load_lds(
      (const __attribute__((address_space(1))) void*)g,
      (__attribute__((address_space(3))) void*)l, 16, 0, 0);
}

// ---------------------------------------------------------------------------
// Kernel 1: per-row L2 norm of embeddings; unit-normalized rows as bf16.
// ---------------------------------------------------------------------------
__global__ __launch_bounds__(64) void k_rownorm(const float* __restrict__ emb,
                                                short* __restrict__ Aunit,
                                                float* __restrict__ norms) {
  const int i = blockIdx.x;
  const int l = threadIdx.x;
  const f32x4* row = reinterpret_cast<const f32x4*>(emb + (size_t)i * D_EMB);
  f32x4 v0 = row[l];
  f32x4 v1 = row[l + 64];
  float ss = sq4(v0) + sq4(v1);
#pragma unroll
  for (int m = 1; m < 64; m <<= 1) ss += __shfl_xor(ss, m);
  float nrm = sqrtf(ss);
  float inv = 1.0f / nrm;
  bf16x4 o0, o1;
#pragma unroll
  for (int q = 0; q < 4; ++q) { o0[q] = f2bf(v0[q] * inv); o1[q] = f2bf(v1[q] * inv); }
  bf16x4* dst = reinterpret_cast<bf16x4*>(Aunit + (size_t)i * D_EMB);
  dst[l] = o0;
  dst[l + 64] = o1;
  if (l == 0) norms[i] = nrm;
}

// ---------------------------------------------------------------------------
// Kernel 2: batch mean / unbiased std -> adaptive margin per row.
// ---------------------------------------------------------------------------
__global__ __launch_bounds__(512) void k_stats(const float* __restrict__ norms,
                                               float* __restrict__ marg) {
  __shared__ float red[8];
  const int t = threadIdx.x;
  const int lane = t & 63, wid = t >> 6;
  float x = norms[t];
  float s = x;
#pragma unroll
  for (int m = 1; m < 64; m <<= 1) s += __shfl_xor(s, m);
  if (lane == 0) red[wid] = s;
  __syncthreads();
  float tot = 0.f;
#pragma unroll
  for (int q = 0; q < 8; ++q) tot += red[q];
  const float mean = tot / 512.f;
  __syncthreads();
  float d = x - mean;
  float s2 = d * d;
#pragma unroll
  for (int m = 1; m < 64; m <<= 1) s2 += __shfl_xor(s2, m);
  if (lane == 0) red[wid] = s2;
  __syncthreads();
  float tot2 = 0.f;
#pragma unroll
  for (int q = 0; q < 8; ++q) tot2 += red[q];
  const float stdv = sqrtf(tot2 / 511.f);   // ddof=1
  float msc = (x - mean) / (stdv + H_F);
  msc = fminf(1.f, fmaxf(-1.f, msc));
  marg[t] = MARGIN_F * (1.f + msc);
}

// ---------------------------------------------------------------------------
// Kernel 3: verified-best k_main (R11/R15): 256 thr, (256,3), 128x128 tile,
// counted-vmcnt 2-deep W pipeline, VGPR 84, no spill; partial row-major.
// ---------------------------------------------------------------------------
__global__ __launch_bounds__(256, 3) void k_main(const short* __restrict__ Aunit,
                                                 const float* __restrict__ weight,
                                                 const int* __restrict__ labels,
                                                 const float* __restrict__ marg,
                                                 float* __restrict__ partial,
                                                 float* __restrict__ tlogit) {
  __shared__ alignas(16) char As[2][8192];     // [128 rows][64 B] bf16, swizzled
  __shared__ alignas(16) char Ws[2][10240];    // [128 cls][80 B] bf16, padded
  __shared__ float winv[128];

  const int bid = blockIdx.x;
  const int grp = bid >> 5, within = bid & 31;
  const int rt = (within >> 3) & 3;            // 0..3
  const int ct = grp * 8 + (within & 7);
  if (ct >= NT2) return;

  const int tid = threadIdx.x;                 // 0..255
  const int w = tid >> 6, lane = tid & 63;
  const int l31 = lane & 31, lhi = lane >> 5;

  // ---- A gload source (pre-swizzled): dest p = w*2048 + i*1024 + lane*16 ----
  const int ar0 = w * 32 + (lane >> 2);
  const int ak0 = ((lane & 3) * 16) ^ (((ar0 >> 1) & 3) << 4);
  const char* gAb0 = (const char*)Aunit + (size_t)(rt * 128 + ar0) * 1024 + ak0;
  const char* gAb1 = gAb0 + (size_t)16 * 1024;

  // ---- W stage roles ----
  const int sc8 = tid >> 3;        // 0..31
  const int su  = tid & 7;         // 0..7
  const float* wbase0; const float* wbase1; const float* wbase2; const float* wbase3;
  int wdst0, wdst1, wdst2, wdst3;
  {
    int c0 = 0 * 32 + sc8, c1 = 1 * 32 + sc8, c2 = 2 * 32 + sc8, c3 = 3 * 32 + sc8;
    int g0 = ct * 128 + c0; if (g0 > C_NUM - 1) g0 = C_NUM - 1;
    int g1 = ct * 128 + c1; if (g1 > C_NUM - 1) g1 = C_NUM - 1;
    int g2 = ct * 128 + c2; if (g2 > C_NUM - 1) g2 = C_NUM - 1;
    int g3 = ct * 128 + c3; if (g3 > C_NUM - 1) g3 = C_NUM - 1;
    wbase0 = weight + (size_t)g0 * D_EMB + su * 4;
    wbase1 = weight + (size_t)g1 * D_EMB + su * 4;
    wbase2 = weight + (size_t)g2 * D_EMB + su * 4;
    wbase3 = weight + (size_t)g3 * D_EMB + su * 4;
    wdst0 = c0 * 80 + su * 8; wdst1 = c1 * 80 + su * 8;
    wdst2 = c2 * 80 + su * 8; wdst3 = c3 * 80 + su * 8;
  }

  // ---- compute-side LDS offsets ----
  const int xa = ((l31 >> 1) & 3) << 4;
  const int abase = (w * 32 + l31) * 64;

  f32x16 acc0, acc1, acc2, acc3;
#pragma unroll
  for (int q = 0; q < 16; ++q) { acc0[q] = 0.f; acc1[q] = 0.f; acc2[q] = 0.f; acc3[q] = 0.f; }
  float ssq0 = 0.f, ssq1 = 0.f, ssq2 = 0.f, ssq3 = 0.f;

  f32x4 pa0, pa1, pa2, pa3;   // one W-chunk reg set
  f32x4 pb0, pb1, pb2, pb3;   // the other

#define WLOAD(R0,R1,R2,R3,OFF) { \
    R0 = *(const f32x4*)(wbase0 + (OFF)); R1 = *(const f32x4*)(wbase1 + (OFF)); \
    R2 = *(const f32x4*)(wbase2 + (OFF)); R3 = *(const f32x4*)(wbase3 + (OFF)); }

#define WWRITE(BUF,R0,R1,R2,R3) { \
    bf16x4 t0, t1, t2, t3; \
    _Pragma("unroll") \
    for (int e = 0; e < 4; ++e) { t0[e] = f2bf(R0[e]); t1[e] = f2bf(R1[e]); \
                                  t2[e] = f2bf(R2[e]); t3[e] = f2bf(R3[e]); } \
    *(bf16x4*)(&Ws[BUF][wdst0]) = t0; *(bf16x4*)(&Ws[BUF][wdst1]) = t1; \
    *(bf16x4*)(&Ws[BUF][wdst2]) = t2; *(bf16x4*)(&Ws[BUF][wdst3]) = t3; }

#define SSQADD(R0,R1,R2,R3) { ssq0 += sq4(R0); ssq1 += sq4(R1); \
                              ssq2 += sq4(R2); ssq3 += sq4(R3); }

#define COMPUTE(BUF) { \
    const char* Ab = As[BUF]; const char* Wb = Ws[BUF]; \
    __builtin_amdgcn_s_setprio(1); \
    _Pragma("unroll") \
    for (int kk = 0; kk < 2; ++kk) { \
      const int kb = kk * 32 + lhi * 16; \
      bf16x8 a  = *(const bf16x8*)(Ab + abase + (kb ^ xa)); \
      bf16x8 b0 = *(const bf16x8*)(Wb + (l31)      * 80 + kb); \
      bf16x8 b1 = *(const bf16x8*)(Wb + (32 + l31) * 80 + kb); \
      bf16x8 b2 = *(const bf16x8*)(Wb + (64 + l31) * 80 + kb); \
      bf16x8 b3 = *(const bf16x8*)(Wb + (96 + l31) * 80 + kb); \
      acc0 = __builtin_amdgcn_mfma_f32_32x32x16_bf16(a, b0, acc0, 0, 0, 0); \
      acc1 = __builtin_amdgcn_mfma_f32_32x32x16_bf16(a, b1, acc1, 0, 0, 0); \
      acc2 = __builtin_amdgcn_mfma_f32_32x32x16_bf16(a, b2, acc2, 0, 0, 0); \
      acc3 = __builtin_amdgcn_mfma_f32_32x32x16_bf16(a, b3, acc3, 0, 0, 0); \
    } \
    __builtin_amdgcn_s_setprio(0); }

  // ---- prologue: pa <- W(0); A(0) -> As[0]; pb <- W(1) ----
  WLOAD(pa0, pa1, pa2, pa3, 0);
  __builtin_amdgcn_sched_barrier(0);
  gload16(gAb0, &As[0][w * 2048]);
  gload16(gAb1, &As[0][w * 2048 + 1024]);
  __builtin_amdgcn_sched_barrier(0);
  WLOAD(pb0, pb1, pb2, pb3, 32);
  __builtin_amdgcn_sched_barrier(0);
  asm volatile("s_waitcnt vmcnt(4)" ::: "memory");   // pa + A(0) done; pb flying
  SSQADD(pa0, pa1, pa2, pa3);
  WWRITE(0, pa0, pa1, pa2, pa3);
  asm volatile("s_waitcnt lgkmcnt(0)" ::: "memory");
  __builtin_amdgcn_s_barrier();
  __builtin_amdgcn_sched_barrier(0);

  for (int i = 0; i < 8; ++i) {
    // ===== even chunk c = 2i: reads As[0]/Ws[0]; pb holds W(2i+1) =====
    {
      const int ao = (2 * i + 1) * 64;                 // A(2i+1), never clamps
      gload16(gAb0 + ao, &As[1][w * 2048]);
      gload16(gAb1 + ao, &As[1][w * 2048 + 1024]);
      __builtin_amdgcn_sched_barrier(0);
      int cw = 2 * i + 2; if (cw > 15) cw = 15;        // W(2i+2) -> pa
      WLOAD(pa0, pa1, pa2, pa3, cw * 32);
      __builtin_amdgcn_sched_barrier(0);
      COMPUTE(0);
      asm volatile("s_waitcnt vmcnt(4)" ::: "memory"); // pb + A(2i+1) done; pa flying
      SSQADD(pb0, pb1, pb2, pb3);                      // W(2i+1), always valid
      WWRITE(1, pb0, pb1, pb2, pb3);
      asm volatile("s_waitcnt lgkmcnt(0)" ::: "memory");
      __builtin_amdgcn_s_barrier();
      __builtin_amdgcn_sched_barrier(0);
    }
    // ===== odd chunk c = 2i+1: reads As[1]/Ws[1]; pa holds W(2i+2) =====
    {
      int ca = 2 * i + 2; if (ca > 15) ca = 15;        // A(2i+2) -> As[0]
      const int ao = ca * 64;
      gload16(gAb0 + ao, &As[0][w * 2048]);
      gload16(gAb1 + ao, &As[0][w * 2048 + 1024]);
      __builtin_amdgcn_sched_barrier(0);
      int cw = 2 * i + 3; if (cw > 15) cw = 15;        // W(2i+3) -> pb
      WLOAD(pb0, pb1, pb2, pb3, cw * 32);
      __builtin_amdgcn_sched_barrier(0);
      COMPUTE(1);
      asm volatile("s_waitcnt vmcnt(4)" ::: "memory"); // pa + A done; pb flying
      if (2 * i + 2 <= 15) SSQADD(pa0, pa1, pa2, pa3); // guard double-count at tail
      WWRITE(0, pa0, pa1, pa2, pa3);
      asm volatile("s_waitcnt lgkmcnt(0)" ::: "memory");
      __builtin_amdgcn_s_barrier();
      __builtin_amdgcn_sched_barrier(0);
    }
  }

  // ---- per-class 1/||w||: reduce over the 8 su units ----
  {
    float s0 = ssq0, s1 = ssq1, s2 = ssq2, s3 = ssq3;
#pragma unroll
    for (int m = 1; m < 8; m <<= 1) {
      s0 += __shfl_xor(s0, m); s1 += __shfl_xor(s1, m);
      s2 += __shfl_xor(s2, m); s3 += __shfl_xor(s3, m);
    }
    if (su == 0) {
      winv[sc8]      = (s0 > 0.f) ? rsqrtf(s0) : 0.f;
      winv[32 + sc8] = (s1 > 0.f) ? rsqrtf(s1) : 0.f;
      winv[64 + sc8] = (s2 > 0.f) ? rsqrtf(s2) : 0.f;
      winv[96 + sc8] = (s3 > 0.f) ? rsqrtf(s3) : 0.f;
    }
  }
  __syncthreads();

  // ---- epilogue: margin at label, per-row exp sums ----
  // C/D layout: col = lane&31, row = (reg&3) + 8*(reg>>2) + 4*(lane>>5)
  const float wv0 = winv[l31];
  const float wv1 = winv[32 + l31];
  const float wv2 = winv[64 + l31];
  const float wv3 = winv[96 + l31];
  const int cb = ct * 128;
#pragma unroll
  for (int r = 0; r < 16; ++r) {
    const int rowf = (r & 3) + 8 * (r >> 2) + 4 * lhi;
    const int R = rt * 128 + w * 32 + rowf;
    const int lab = labels[R];
    float v = 0.f;
#pragma unroll
    for (int ni = 0; ni < 4; ++ni) {
      const int gcc = cb + ni * 32 + l31;
      const float wv = (ni == 0) ? wv0 : (ni == 1) ? wv1 : (ni == 2) ? wv2 : wv3;
      const float av = (ni == 0) ? acc0[r] : (ni == 1) ? acc1[r] : (ni == 2) ? acc2[r] : acc3[r];
      const float cosv = av * wv;
      float lg = SCALE_F * cosv;
      if (lab == gcc) {
        float ctv = fminf(1.f, fmaxf(-1.f, cosv));
        float lt = SCALE_F * cosf(acosf(ctv) + marg[R]);
        lg = lt;
        tlogit[R] = lt;
      }
      v += (gcc < C_NUM) ? __expf(lg) : 0.f;
    }
    v += __shfl_xor(v, 1);
    v += __shfl_xor(v, 2);
    v += __shfl_xor(v, 4);
    v += __shfl_xor(v, 8);
    v += __shfl_xor(v, 16);
    if (l31 == 0) partial[(size_t)R * PST + ct] = v;   // row-major -> coalesced reduce
  }
#undef WLOAD
#undef WWRITE
#undef SSQADD
#undef COMPUTE
}

// ---------------------------------------------------------------------------
// Kernel 4: per-row reduce (coalesced): term[r] = log(sum_ct partial[r][ct]) - tlogit[r]
// ---------------------------------------------------------------------------
__global__ __launch_bounds__(64) void k_reduce(const float* __restrict__ partial,
                                               const float* __restrict__ tlogit,
                                               float* __restrict__ term) {
  const int r = blockIdx.x;
  const int l = threadIdx.x;
  const float* row = partial + (size_t)r * PST;
  float s = 0.f;
  for (int b = l; b < NT2; b += 64)
    s += row[b];
#pragma unroll
  for (int m = 1; m < 64; m <<= 1) s += __shfl_xor(s, m);
  if (l == 0) term[r] = logf(s) - tlogit[r];
}

// ---------------------------------------------------------------------------
// Kernel 5: loss = mean(term)
// ---------------------------------------------------------------------------
__global__ __launch_bounds__(512) void k_final(const float* __restrict__ term,
                                               float* __restrict__ out) {
  __shared__ float red[8];
  const int t = threadIdx.x;
  const int lane = t & 63, wid = t >> 6;
  float v = term[t];
#pragma unroll
  for (int m = 1; m < 64; m <<= 1) v += __shfl_xor(v, m);
  if (lane == 0) red[wid] = v;
  __syncthreads();
  if (t == 0) {
    float tot = 0.f;
#pragma unroll
    for (int q = 0; q < 8; ++q) tot += red[q];
    out[0] = tot / 512.f;
  }
}

extern "C" void kernel_launch(void* const* d_in, const int* in_sizes, int n_in,
                              void* d_out, int out_size, void* d_ws, size_t ws_size,
                              hipStream_t stream) {
  const float* emb    = (const float*)d_in[0];
  const int*   labels = (const int*)d_in[1];
  const float* weight = (const float*)d_in[2];
  float* out = (float*)d_out;

  char* ws = (char*)d_ws;
  short* Aunit   = (short*)ws;                        // 512*512*2 = 524288 B
  float* norms   = (float*)(ws + 524288);             // 2 KiB
  float* marg    = (float*)(ws + 524288 + 2048);      // 2 KiB
  float* tlog    = (float*)(ws + 524288 + 4096);      // 2 KiB
  float* term    = (float*)(ws + 524288 + 6144);      // 2 KiB
  float* partial = (float*)(ws + 524288 + 8192);      // 512*784*4 = 1605632 B

  k_rownorm<<<N_BATCH, 64, 0, stream>>>(emb, Aunit, norms);
  k_stats<<<1, 512, 0, stream>>>(norms, marg);
  k_main<<<98 * 32, 256, 0, stream>>>(Aunit, weight, labels, marg, partial, tlog);
  k_reduce<<<N_BATCH, 64, 0, stream>>>(partial, tlog, term);
  k_final<<<1, 512, 0, stream>>>(term, out);
}